// Round 5
// baseline (7969.892 us; speedup 1.0000x reference)
//
#include <hip/hip_runtime.h>
#include <cstdint>
#include <cstddef>

#define NN 500
#define KP 512   // node dim padded to 512 for f16 MFMA operands

typedef _Float16 f16;
typedef _Float16 half8 __attribute__((ext_vector_type(8)));
typedef float floatx4 __attribute__((ext_vector_type(4)));

// 8 A-sharing groups; each: acc += A*B1^T (+ A*B2^T). 12 passes total.
struct MSet {
  const f16* A[8];
  const f16* B1[8];
  const f16* B2[8];   // nullptr -> single-B group
  int ngroups;
};

// ---------------------------------------------------------------------------
// adp = softmax(relu(E1 @ E2), axis=1)
__global__ __launch_bounds__(256) void adp_kernel(const float* __restrict__ e1,
                                                  const float* __restrict__ e2,
                                                  float* __restrict__ adp) {
  int r = blockIdx.x;
  int tid = threadIdx.x;
  __shared__ float red[256];
  __shared__ float e1row[16];
  if (tid < 10) e1row[tid] = e1[r * 10 + tid];
  __syncthreads();
  float z0, z1 = 0.f;
  {
    float acc = 0.f;
#pragma unroll
    for (int k = 0; k < 10; k++) acc += e1row[k] * e2[k * NN + tid];
    z0 = fmaxf(acc, 0.f);
  }
  bool has1 = (tid + 256) < NN;
  if (has1) {
    float acc = 0.f;
#pragma unroll
    for (int k = 0; k < 10; k++) acc += e1row[k] * e2[k * NN + tid + 256];
    z1 = fmaxf(acc, 0.f);
  }
  float mx = has1 ? fmaxf(z0, z1) : z0;
  red[tid] = mx;
  __syncthreads();
  for (int s = 128; s > 0; s >>= 1) {
    if (tid < s) red[tid] = fmaxf(red[tid], red[tid + s]);
    __syncthreads();
  }
  mx = red[0];
  __syncthreads();
  float ex0 = __expf(z0 - mx);
  float ex1 = has1 ? __expf(z1 - mx) : 0.f;
  red[tid] = ex0 + ex1;
  __syncthreads();
  for (int s = 128; s > 0; s >>= 1) {
    if (tid < s) red[tid] += red[tid + s];
    __syncthreads();
  }
  float inv = 1.f / red[0];
  adp[r * NN + tid] = ex0 * inv;
  if (has1) adp[r * NN + tid + 256] = ex1 * inv;
}

// ---------------------------------------------------------------------------
// B^T as f16 hi/lo pair: hi[w][v]+lo[w][v] ~= src[v][w], 512x512 zero-padded.
__global__ __launch_bounds__(256) void bt_kernel(const float* __restrict__ src,
                                                 f16* __restrict__ hi,
                                                 f16* __restrict__ lo) {
  int idx = blockIdx.x * 256 + threadIdx.x;  // 512*512 total
  int w = idx >> 9, v = idx & 511;
  float x = (w < NN && v < NN) ? src[v * NN + w] : 0.f;
  f16 h = (f16)x;
  hi[idx] = h;
  lo[idx] = (f16)(x - (float)h);
}

// ---------------------------------------------------------------------------
// Squared-matrix B^T pair: dst[w][v] = (src @ src)[v][w] = sum_u src[v,u]*src[u,w].
// One block (512 thr) per (v, which); w = threadIdx (coalesced inner reads).
__global__ __launch_bounds__(512) void sq_kernel(const float* __restrict__ srcA,
                                                 const float* __restrict__ srcB,
                                                 f16* __restrict__ hiA, f16* __restrict__ loA,
                                                 f16* __restrict__ hiB, f16* __restrict__ loB) {
  const float* src = blockIdx.y == 0 ? srcA : srcB;
  f16* hi = blockIdx.y == 0 ? hiA : hiB;
  f16* lo = blockIdx.y == 0 ? loA : loB;
  int v = blockIdx.x;   // 0..511
  int w = threadIdx.x;  // 0..511
  __shared__ float vrow[512];
  vrow[w] = (v < NN && w < NN) ? src[v * NN + w] : 0.f;
  __syncthreads();
  float acc = 0.f;
  if (v < NN && w < NN) {
#pragma unroll 4
    for (int u = 0; u < NN; u++) acc = fmaf(vrow[u], src[u * NN + w], acc);
  }
  size_t o = (size_t)w * 512 + v;
  f16 h = (f16)acc;
  hi[o] = h;
  lo[o] = (f16)(acc - (float)h);
}

// ---------------------------------------------------------------------------
// Zero the pad columns [500,512) of the eight f16 P arrays (ws re-poisoned 0xAA).
__global__ __launch_bounds__(256) void padzero_kernel(uint32_t* __restrict__ slab, int R) {
  int idx = blockIdx.x * 256 + threadIdx.x;
  int total = 8 * R * 6;
  if (idx >= total) return;
  int a = idx / (R * 6);
  int rem = idx - a * R * 6;
  int row = rem / 6;
  int q = rem - row * 6;
  slab[(size_t)a * R * 256 + (size_t)row * 256 + 250 + q] = 0u;
}

// ---------------------------------------------------------------------------
__global__ __launch_bounds__(256) void start_conv_kernel(const float* __restrict__ x,
    const float* __restrict__ w, const float* __restrict__ bias,
    float* __restrict__ h0, int b0) {
  int nc = blockIdx.x, t = blockIdx.y, bb = blockIdx.z;
  int n = nc * 256 + threadIdx.x;
  if (n >= NN) return;
  int babs = b0 + bb;
  float x0 = x[(((size_t)babs * 2 + 0) * NN + n) * 256 + t];
  float x1 = x[(((size_t)babs * 2 + 1) * NN + n) * 256 + t];
#pragma unroll
  for (int c = 0; c < 32; c++) {
    h0[(((size_t)bb * 32 + c) * 256 + t) * NN + n] = bias[c] + w[c * 2] * x0 + w[c * 2 + 1] * x1;
  }
}

// ---------------------------------------------------------------------------
// Fused dilated-conv + gating + GCN channel-mix. FG lives in registers only.
// Outputs: Hout fp32 (GEMM Cin), and P1a/P2a/P1b/P2b as f16 hi/lo pairs.
// All register-array loops fully unrolled (scratch-demotion hazard, round-1).
__global__ __launch_bounds__(256) void dcm_kernel(
    const float* __restrict__ hprev,
    const float* __restrict__ fw, const float* __restrict__ fb,
    const float* __restrict__ gw, const float* __restrict__ gb,
    const float* __restrict__ cw, const float* __restrict__ cb,
    float* __restrict__ Hout,
    f16* __restrict__ P1aH, f16* __restrict__ P1aL,
    f16* __restrict__ P2aH, f16* __restrict__ P2aL,
    f16* __restrict__ P1bH, f16* __restrict__ P1bL,
    f16* __restrict__ P2bH, f16* __restrict__ P2bL,
    float* __restrict__ tapL,
    int Lp, int L, int b0) {
  int nc = blockIdx.x, j = blockIdx.y, bb = blockIdx.z;
  int n = nc * 256 + threadIdx.x;
  if (n >= NN) return;
  size_t base = ((size_t)(bb * 32) * Lp + 2 * j) * NN + n;
  size_t cs = (size_t)Lp * NN;
  float FG[32];
#pragma unroll
  for (int half = 0; half < 2; half++) {
    float accf[16], accg[16];
#pragma unroll
    for (int c = 0; c < 16; c++) {
      accf[c] = fb[half * 16 + c];
      accg[c] = gb[half * 16 + c];
    }
    for (int cp = 0; cp < 32; cp++) {
      float v0 = hprev[base + cp * cs];
      float v1 = hprev[base + cp * cs + NN];
      const float* fwp = fw + (half * 16) * 64 + cp * 2;  // [c][cp][tap]
      const float* gwp = gw + (half * 16) * 64 + cp * 2;
#pragma unroll
      for (int c = 0; c < 16; c++) {
        accf[c] = fmaf(fwp[c * 64], v0, accf[c]);
        accf[c] = fmaf(fwp[c * 64 + 1], v1, accf[c]);
        accg[c] = fmaf(gwp[c * 64], v0, accg[c]);
        accg[c] = fmaf(gwp[c * 64 + 1], v1, accg[c]);
      }
    }
#pragma unroll
    for (int c = 0; c < 16; c++) {
      float E = __expf(2.f * accf[c]);
      float th = 1.f - 2.f / (E + 1.f);          // tanh
      float sg = 1.f / (1.f + __expf(-accg[c])); // sigmoid
      FG[half * 16 + c] = th * sg;
    }
  }
  if (j == L - 1) {
    size_t tbase = ((size_t)(b0 + bb) * 32) * NN + n;
#pragma unroll
    for (int c = 0; c < 32; c++) tapL[tbase + (size_t)c * NN] = FG[c];
  }
  if (Hout == nullptr) return;  // layer 8: only the skip tap survives
#pragma unroll 2
  for (int c = 0; c < 32; c++) {
    const float* wr = cw + c * 160;
    float h = cb[c], p1 = 0.f, p2 = 0.f, q1 = 0.f, q2 = 0.f;
#pragma unroll
    for (int cp = 0; cp < 32; cp++) {
      float f = FG[cp];
      h  = fmaf(wr[cp], f, h);
      p1 = fmaf(wr[32 + cp], f, p1);
      p2 = fmaf(wr[64 + cp], f, p2);
      q1 = fmaf(wr[96 + cp], f, q1);
      q2 = fmaf(wr[128 + cp], f, q2);
    }
    h += hprev[((size_t)(bb * 32 + c) * Lp + 2 * j + 1) * NN + n];  // residual
    size_t mi = (size_t)(bb * 32 + c) * L + j;
    Hout[mi * NN + n] = h;
    size_t o = mi * KP + n;
    f16 t;
    t = (f16)p1; P1aH[o] = t; P1aL[o] = (f16)(p1 - (float)t);
    t = (f16)p2; P2aH[o] = t; P2aL[o] = (f16)(p2 - (float)t);
    t = (f16)q1; P1bH[o] = t; P1bL[o] = (f16)(q1 - (float)t);
    t = (f16)q2; P2bH[o] = t; P2bL[o] = (f16)(q2 - (float)t);
  }
}

// ---------------------------------------------------------------------------
// Fused GCN node-mix GEMM with LDS staging + register prefetch:
//   Out[m,w] = BN( Cin[m,w] + sum_groups sum_B A_g[m,:] . B[w,:] )
// Block 128m x 256n; 4 waves of 64m x 128n (4x8 subtiles of mfma 16x16x32).
// Strips: A 128x32, B 256x32 (hi + optional lo), rows padded to 40 f16
// (2-way bank aliasing only). Prefetch strip k+1 into regs before compute(k).
__global__ __launch_bounds__(256, 2) void mfma_gcn(MSet s,
    const float* __restrict__ Cin, float* __restrict__ Out, int M,
    const float* __restrict__ bng, const float* __restrict__ bnb, int lshift) {
  __shared__ f16 As[128 * 40];
  __shared__ f16 B1s[256 * 40];
  __shared__ f16 B2s[256 * 40];
  int t = threadIdx.x;
  int wave = t >> 6, lane = t & 63;
  int wm = wave >> 1, wn = wave & 1;
  int mB = blockIdx.y * 128;
  int nB = blockIdx.x * 256;
  int lm = lane & 15, kq = lane >> 4;
  int srow = t >> 2, schunk = t & 3;  // staging: 4 lanes per row (64B coalesced)
  floatx4 acc[4][8];
#pragma unroll
  for (int i = 0; i < 4; i++)
#pragma unroll
    for (int j = 0; j < 8; j++) acc[i][j] = (floatx4){0.f, 0.f, 0.f, 0.f};

  // global row indices for staging (A clamped to M-1; epilogue guards rows)
  size_t agr[2];
#pragma unroll
  for (int it = 0; it < 2; it++) {
    int r = mB + it * 64 + srow;
    agr[it] = (size_t)(r < M ? r : M - 1) * KP + schunk * 8;
  }
  size_t bgr[4];
#pragma unroll
  for (int it = 0; it < 4; it++) bgr[it] = (size_t)(nB + it * 64 + srow) * KP + schunk * 8;

  for (int gi = 0; gi < s.ngroups; gi++) {
    const f16* __restrict__ Ap = s.A[gi];
    const f16* __restrict__ B1p = s.B1[gi];
    const f16* __restrict__ B2p = s.B2[gi];
    bool has2 = (B2p != nullptr);
    float4 pA[2], pB1[4], pB2[4];
    // prefetch strip 0
#pragma unroll
    for (int it = 0; it < 2; it++) pA[it] = *(const float4*)(Ap + agr[it]);
#pragma unroll
    for (int it = 0; it < 4; it++) pB1[it] = *(const float4*)(B1p + bgr[it]);
    if (has2) {
#pragma unroll
      for (int it = 0; it < 4; it++) pB2[it] = *(const float4*)(B2p + bgr[it]);
    }
    for (int kt = 0; kt < 16; kt++) {
      __syncthreads();
#pragma unroll
      for (int it = 0; it < 2; it++)
        *(float4*)(As + (it * 64 + srow) * 40 + schunk * 8) = pA[it];
#pragma unroll
      for (int it = 0; it < 4; it++)
        *(float4*)(B1s + (it * 64 + srow) * 40 + schunk * 8) = pB1[it];
      if (has2) {
#pragma unroll
        for (int it = 0; it < 4; it++)
          *(float4*)(B2s + (it * 64 + srow) * 40 + schunk * 8) = pB2[it];
      }
      __syncthreads();
      // prefetch next strip (clamped re-load of last strip on final iter)
      int kn = (kt < 15) ? (kt + 1) * 32 : 15 * 32;
#pragma unroll
      for (int it = 0; it < 2; it++) pA[it] = *(const float4*)(Ap + agr[it] + kn);
#pragma unroll
      for (int it = 0; it < 4; it++) pB1[it] = *(const float4*)(B1p + bgr[it] + kn);
      if (has2) {
#pragma unroll
        for (int it = 0; it < 4; it++) pB2[it] = *(const float4*)(B2p + bgr[it] + kn);
      }
      // compute current strip from LDS
      half8 av[4];
#pragma unroll
      for (int i = 0; i < 4; i++)
        av[i] = *(const half8*)(As + (wm * 64 + i * 16 + lm) * 40 + kq * 8);
#pragma unroll
      for (int j = 0; j < 8; j++) {
        half8 b1 = *(const half8*)(B1s + (wn * 128 + j * 16 + lm) * 40 + kq * 8);
#pragma unroll
        for (int i = 0; i < 4; i++)
          acc[i][j] = __builtin_amdgcn_mfma_f32_16x16x32_f16(av[i], b1, acc[i][j], 0, 0, 0);
      }
      if (has2) {
#pragma unroll
        for (int j = 0; j < 8; j++) {
          half8 b2 = *(const half8*)(B2s + (wn * 128 + j * 16 + lm) * 40 + kq * 8);
#pragma unroll
          for (int i = 0; i < 4; i++)
            acc[i][j] = __builtin_amdgcn_mfma_f32_16x16x32_f16(av[i], b2, acc[i][j], 0, 0, 0);
        }
      }
    }
  }
  // epilogue: C/D layout col = lane&15, row = (lane>>4)*4 + reg
  int cn = lane & 15, rq = lane >> 4;
  float rs = rsqrtf(1.f + 1e-5f);
#pragma unroll
  for (int i = 0; i < 4; i++) {
#pragma unroll
    for (int r = 0; r < 4; r++) {
      int row = mB + wm * 64 + i * 16 + rq * 4 + r;
      if (row < M) {
        int c = (row >> lshift) & 31;  // m = (bb*32+c)*L + j
        float scale = bng[c] * rs;
        float bias = bnb[c];
#pragma unroll
        for (int j = 0; j < 8; j++) {
          int col = nB + wn * 128 + j * 16 + cn;
          if (col < NN) {
            size_t o = (size_t)row * NN + col;
            Out[o] = (acc[i][j][r] + Cin[o]) * scale + bias;
          }
        }
      }
    }
  }
}

// ---------------------------------------------------------------------------
// skip -> relu -> end1 -> relu -> end2. One block per (b, 20 n-values).
#define NB 20
#define NBP 21
__global__ __launch_bounds__(256) void final_kernel(const float* __restrict__ tap,
    const float* __restrict__ skw, const float* __restrict__ skb,
    const float* __restrict__ e1w, const float* __restrict__ e1b,
    const float* __restrict__ e2w, const float* __restrict__ e2b,
    float* __restrict__ out) {
  __shared__ float tapS[256][NBP];
  __shared__ float skS[256][NBP];
  __shared__ float e1S[512][NBP];
  int tid = threadIdx.x;
  int b = blockIdx.y;
  int n0 = blockIdx.x * NB;
  {
    int i = tid >> 5, c = tid & 31;
    const float* tp = tap + (((size_t)i * 8 + b) * 32 + c) * NN + n0;
#pragma unroll
    for (int v = 0; v < NB; v++) tapS[tid][v] = tp[v];
  }
  __syncthreads();
  {
    float bsum = 0.f;
#pragma unroll
    for (int i2 = 0; i2 < 8; i2++) bsum += skb[i2 * 256 + tid];
    float acc[NB];
#pragma unroll
    for (int v = 0; v < NB; v++) acc[v] = bsum;
#pragma unroll
    for (int i2 = 0; i2 < 8; i2++) {
      const float* wr = skw + ((size_t)i2 * 256 + tid) * 32;
#pragma unroll
      for (int cp = 0; cp < 32; cp++) {
        float w = wr[cp];
#pragma unroll
        for (int v = 0; v < NB; v++) acc[v] = fmaf(w, tapS[i2 * 32 + cp][v], acc[v]);
      }
    }
#pragma unroll
    for (int v = 0; v < NB; v++) skS[tid][v] = fmaxf(acc[v], 0.f);
  }
  __syncthreads();
#pragma unroll
  for (int h = 0; h < 2; h++) {
    int k = tid + h * 256;
    float bv = e1b[k];
    float acc[NB];
#pragma unroll
    for (int v = 0; v < NB; v++) acc[v] = bv;
    const float* wr = e1w + (size_t)k * 256;
    for (int o = 0; o < 256; o++) {
      float w = wr[o];
#pragma unroll
      for (int v = 0; v < NB; v++) acc[v] = fmaf(w, skS[o][v], acc[v]);
    }
#pragma unroll
    for (int v = 0; v < NB; v++) e1S[k][v] = fmaxf(acc[v], 0.f);
  }
  __syncthreads();
  if (tid < 12 * NB) {
    int q = tid / NB, v = tid % NB;
    float acc = e2b[q];
    const float* wr = e2w + (size_t)q * 512;
#pragma unroll 8
    for (int k = 0; k < 512; k++) acc = fmaf(wr[k], e1S[k][v], acc);
    out[((size_t)b * 12 + q) * NN + n0 + v] = acc;
  }
}

// ---------------------------------------------------------------------------
extern "C" void kernel_launch(void* const* d_in, const int* in_sizes, int n_in,
                              void* d_out, int out_size, void* d_ws, size_t ws_size,
                              hipStream_t stream) {
  const float* x       = (const float*)d_in[0];
  const float* A0      = (const float*)d_in[1];
  const float* start_w = (const float*)d_in[2];
  const float* start_b = (const float*)d_in[3];
  const float* filt_w  = (const float*)d_in[4];
  const float* filt_b  = (const float*)d_in[5];
  const float* gate_w  = (const float*)d_in[6];
  const float* gate_b  = (const float*)d_in[7];
  const float* skip_w  = (const float*)d_in[8];
  const float* skip_b  = (const float*)d_in[9];
  const float* gcn_w   = (const float*)d_in[10];
  const float* gcn_b   = (const float*)d_in[11];
  const float* bn_g    = (const float*)d_in[12];
  const float* bn_b    = (const float*)d_in[13];
  const float* nv1     = (const float*)d_in[14];
  const float* nv2     = (const float*)d_in[15];
  const float* e1w     = (const float*)d_in[16];
  const float* e1b     = (const float*)d_in[17];
  const float* e2w     = (const float*)d_in[18];
  const float* e2b     = (const float*)d_in[19];
  float* out = (float*)d_out;

  char* ws = (char*)d_ws;
  size_t off = 0;
  auto alloc = [&](size_t bytes) -> void* {
    void* p = (void*)(ws + off);
    off += (bytes + 255) & ~(size_t)255;
    return p;
  };
  float* adp   = (float*)alloc((size_t)NN * NN * 4);
  float* tap   = (float*)alloc((size_t)8 * 8 * 32 * NN * 4);
  f16*   A0tH  = (f16*)alloc((size_t)KP * KP * 2);
  f16*   A0tL  = (f16*)alloc((size_t)KP * KP * 2);
  f16*   adptH = (f16*)alloc((size_t)KP * KP * 2);
  f16*   adptL = (f16*)alloc((size_t)KP * KP * 2);
  f16*   Q0H   = (f16*)alloc((size_t)KP * KP * 2);   // (A0^2)^T pair
  f16*   Q0L   = (f16*)alloc((size_t)KP * KP * 2);
  f16*   QdH   = (f16*)alloc((size_t)KP * KP * 2);   // (adp^2)^T pair
  f16*   QdL   = (f16*)alloc((size_t)KP * KP * 2);
  size_t fixed = off;
  // per-batch: hA fp32 (L<=256) + hB fp32 (L<=128) + 8 f16 arrays [32*128 x 512]
  const size_t perg = 16384000ull + 8192000ull + 8ull * 4194304ull;  // 58.1 MB
  int g = 8;
  while (g > 1 && fixed + (size_t)g * perg + 65536 > ws_size) g >>= 1;
  float* hA  = (float*)alloc((size_t)g * 16384000ull);
  float* hB  = (float*)alloc((size_t)g * 8192000ull);
  f16* slab  = (f16*)alloc(8ull * g * 4194304ull);
  int R = g * 4096;  // rows per f16 array (layer-0 M)
  f16* P1aH = slab + 0ull * R * KP;
  f16* P1aL = slab + 1ull * R * KP;
  f16* P2aH = slab + 2ull * R * KP;
  f16* P2aL = slab + 3ull * R * KP;
  f16* P1bH = slab + 4ull * R * KP;
  f16* P1bL = slab + 5ull * R * KP;
  f16* P2bH = slab + 6ull * R * KP;
  f16* P2bL = slab + 7ull * R * KP;

  adp_kernel<<<NN, 256, 0, stream>>>(nv1, nv2, adp);
  bt_kernel<<<1024, 256, 0, stream>>>(A0, A0tH, A0tL);
  bt_kernel<<<1024, 256, 0, stream>>>(adp, adptH, adptL);
  sq_kernel<<<dim3(512, 2), 512, 0, stream>>>(A0, adp, Q0H, Q0L, QdH, QdL);
  padzero_kernel<<<(48 * R + 255) / 256, 256, 0, stream>>>((uint32_t*)slab, R);

  // group list: out = H + P1a*A0 + P2a*A0^2 + P1b*adp + P2b*adp^2, each
  // operand as f16 hi/lo pair, 3 correction passes per product (drop lo*lo).
  MSet s{};
  s.A[0] = P1aH; s.B1[0] = A0tH;  s.B2[0] = A0tL;
  s.A[1] = P1aL; s.B1[1] = A0tH;  s.B2[1] = nullptr;
  s.A[2] = P2aH; s.B1[2] = Q0H;   s.B2[2] = Q0L;
  s.A[3] = P2aL; s.B1[3] = Q0H;   s.B2[3] = nullptr;
  s.A[4] = P1bH; s.B1[4] = adptH; s.B2[4] = adptL;
  s.A[5] = P1bL; s.B1[5] = adptH; s.B2[5] = nullptr;
  s.A[6] = P2bH; s.B1[6] = QdH;   s.B2[6] = QdL;
  s.A[7] = P2bL; s.B1[7] = QdH;   s.B2[7] = nullptr;
  s.ngroups = 8;

  for (int b0 = 0; b0 < 8; b0 += g) {
    start_conv_kernel<<<dim3(2, 256, g), 256, 0, stream>>>(x, start_w, start_b, hA, b0);
    float* hprev = hA;
    int Lp = 256;
    for (int i = 0; i < 8; i++) {
      int L = Lp >> 1;  // 128,64,...,1
      if (i < 7) {
        float* hout = (i & 1) ? hA : hB;
        dcm_kernel<<<dim3(2, L, g), 256, 0, stream>>>(
            hprev, filt_w + i * 2048, filt_b + i * 32, gate_w + i * 2048, gate_b + i * 32,
            gcn_w + i * 5120, gcn_b + i * 32, hout,
            P1aH, P1aL, P2aH, P2aL, P1bH, P1bL, P2bH, P2bL,
            tap + (size_t)i * 8 * 32 * NN, Lp, L, b0);
        int M = g * 32 * L;
        int Mb = (M + 127) / 128;
        mfma_gcn<<<dim3(2, Mb), 256, 0, stream>>>(s, hout, hout, M,
                                                  bn_g + i * 32, bn_b + i * 32, 7 - i);
        hprev = hout;
        Lp = L;
      } else {
        // layer 8: only the skip tap survives
        dcm_kernel<<<dim3(2, 1, g), 256, 0, stream>>>(
            hprev, filt_w + i * 2048, filt_b + i * 32, gate_w + i * 2048, gate_b + i * 32,
            gcn_w, gcn_b, nullptr,
            P1aH, P1aL, P2aH, P2aL, P1bH, P1bL, P2bH, P2bL,
            tap + (size_t)i * 8 * 32 * NN, Lp, 1, b0);
      }
    }
  }
  final_kernel<<<dim3(25, 8), 256, 0, stream>>>(tap, skip_w, skip_b, e1w, e1b, e2w, e2b, out);
}

// Round 6
// 4818.286 us; speedup vs baseline: 1.6541x; 1.6541x over previous
//
#include <hip/hip_runtime.h>
#include <cstdint>
#include <cstddef>

#define NN 500
#define KP 512   // node dim padded to 512 for f16 MFMA operands

typedef _Float16 f16;
typedef _Float16 half8 __attribute__((ext_vector_type(8)));
typedef float floatx4 __attribute__((ext_vector_type(4)));

// 8 A-sharing groups; each: acc += A*B1^T (+ A*B2^T). 12 MFMA passes, 8 A reads.
struct MSet {
  const f16* A[8];
  const f16* B1[8];
  const f16* B2[8];   // nullptr -> single-B group
};

// ---------------------------------------------------------------------------
// adp = softmax(relu(E1 @ E2), axis=1)
__global__ __launch_bounds__(256) void adp_kernel(const float* __restrict__ e1,
                                                  const float* __restrict__ e2,
                                                  float* __restrict__ adp) {
  int r = blockIdx.x;
  int tid = threadIdx.x;
  __shared__ float red[256];
  __shared__ float e1row[16];
  if (tid < 10) e1row[tid] = e1[r * 10 + tid];
  __syncthreads();
  float z0, z1 = 0.f;
  {
    float acc = 0.f;
#pragma unroll
    for (int k = 0; k < 10; k++) acc += e1row[k] * e2[k * NN + tid];
    z0 = fmaxf(acc, 0.f);
  }
  bool has1 = (tid + 256) < NN;
  if (has1) {
    float acc = 0.f;
#pragma unroll
    for (int k = 0; k < 10; k++) acc += e1row[k] * e2[k * NN + tid + 256];
    z1 = fmaxf(acc, 0.f);
  }
  float mx = has1 ? fmaxf(z0, z1) : z0;
  red[tid] = mx;
  __syncthreads();
  for (int s = 128; s > 0; s >>= 1) {
    if (tid < s) red[tid] = fmaxf(red[tid], red[tid + s]);
    __syncthreads();
  }
  mx = red[0];
  __syncthreads();
  float ex0 = __expf(z0 - mx);
  float ex1 = has1 ? __expf(z1 - mx) : 0.f;
  red[tid] = ex0 + ex1;
  __syncthreads();
  for (int s = 128; s > 0; s >>= 1) {
    if (tid < s) red[tid] += red[tid + s];
    __syncthreads();
  }
  float inv = 1.f / red[0];
  adp[r * NN + tid] = ex0 * inv;
  if (has1) adp[r * NN + tid + 256] = ex1 * inv;
}

// ---------------------------------------------------------------------------
// xT[bc][t][n] = x[bc][n][t]  (coalesced reads for the fused layer-0 dconv)
__global__ __launch_bounds__(256) void xt_kernel(const float* __restrict__ x,
                                                 float* __restrict__ xT) {
  __shared__ float tile[32][33];
  int tx = threadIdx.x & 31, ty = threadIdx.x >> 5;
  int n0 = blockIdx.x * 32, t0 = blockIdx.y * 32, bc = blockIdx.z;
#pragma unroll
  for (int rr = 0; rr < 4; rr++) {
    int n = n0 + ty + rr * 8, t = t0 + tx;
    tile[ty + rr * 8][tx] = (n < NN) ? x[((size_t)bc * NN + n) * 256 + t] : 0.f;
  }
  __syncthreads();
#pragma unroll
  for (int rr = 0; rr < 4; rr++) {
    int t = t0 + ty + rr * 8, n = n0 + tx;
    if (n < NN) xT[((size_t)bc * 256 + t) * NN + n] = tile[tx][ty + rr * 8];
  }
}

// ---------------------------------------------------------------------------
// B^T as f16 hi/lo pair: hi[w][v]+lo[w][v] ~= src[v][w], 512x512 zero-padded.
__global__ __launch_bounds__(256) void bt_kernel(const float* __restrict__ src,
                                                 f16* __restrict__ hi,
                                                 f16* __restrict__ lo) {
  int idx = blockIdx.x * 256 + threadIdx.x;  // 512*512 total
  int w = idx >> 9, v = idx & 511;
  float x = (w < NN && v < NN) ? src[v * NN + w] : 0.f;
  f16 h = (f16)x;
  hi[idx] = h;
  lo[idx] = (f16)(x - (float)h);
}

// ---------------------------------------------------------------------------
// Squared-matrix B^T pair: dst[w][v] = (src @ src)[v][w].
__global__ __launch_bounds__(512) void sq_kernel(const float* __restrict__ srcA,
                                                 const float* __restrict__ srcB,
                                                 f16* __restrict__ hiA, f16* __restrict__ loA,
                                                 f16* __restrict__ hiB, f16* __restrict__ loB) {
  const float* src = blockIdx.y == 0 ? srcA : srcB;
  f16* hi = blockIdx.y == 0 ? hiA : hiB;
  f16* lo = blockIdx.y == 0 ? loA : loB;
  int v = blockIdx.x;   // 0..511
  int w = threadIdx.x;  // 0..511
  __shared__ float vrow[512];
  vrow[w] = (v < NN && w < NN) ? src[v * NN + w] : 0.f;
  __syncthreads();
  float acc = 0.f;
  if (v < NN && w < NN) {
#pragma unroll 4
    for (int u = 0; u < NN; u++) acc = fmaf(vrow[u], src[u * NN + w], acc);
  }
  size_t o = (size_t)w * 512 + v;
  f16 h = (f16)acc;
  hi[o] = h;
  lo[o] = (f16)(acc - (float)h);
}

// ---------------------------------------------------------------------------
// Zero pad columns [500,512) of the eight f16 P arrays (ws re-poisoned 0xAA).
__global__ __launch_bounds__(256) void padzero_kernel(uint32_t* __restrict__ slab, int R) {
  int idx = blockIdx.x * 256 + threadIdx.x;
  int total = 8 * R * 6;
  if (idx >= total) return;
  int a = idx / (R * 6);
  int rem = idx - a * R * 6;
  int row = rem / 6;
  int q = rem - row * 6;
  slab[(size_t)a * R * 256 + (size_t)row * 256 + 250 + q] = 0u;
}

// ---------------------------------------------------------------------------
// Fused (start-conv) + dilated-conv + gating + GCN channel-mix. FG in registers.
// FUSED=true (layer 0): h comes from start-conv of xT on the fly (no h0 buffer).
// Outputs: Hout fp32 (GEMM Cin incl. residual), P arrays as f16 hi/lo pairs.
// All register-array index loops fully unrolled (scratch-demotion hazard, r1).
template <bool FUSED>
__global__ __launch_bounds__(256) void dcm_kernel(
    const float* __restrict__ hprev, const float* __restrict__ xT,
    const float* __restrict__ sw, const float* __restrict__ sb,
    const float* __restrict__ fw, const float* __restrict__ fb,
    const float* __restrict__ gw, const float* __restrict__ gb,
    const float* __restrict__ cw, const float* __restrict__ cb,
    float* __restrict__ Hout,
    f16* __restrict__ P1aH, f16* __restrict__ P1aL,
    f16* __restrict__ P2aH, f16* __restrict__ P2aL,
    f16* __restrict__ P1bH, f16* __restrict__ P1bL,
    f16* __restrict__ P2bH, f16* __restrict__ P2bL,
    float* __restrict__ tapL,
    int Lp, int L, int b0) {
  int nc = blockIdx.x, j = blockIdx.y, bb = blockIdx.z;
  int n = nc * 256 + threadIdx.x;
  if (n >= NN) return;
  size_t base = ((size_t)(bb * 32) * Lp + 2 * j) * NN + n;
  size_t cs = (size_t)Lp * NN;
  float x00 = 0.f, x01 = 0.f, x10 = 0.f, x11 = 0.f;
  if (FUSED) {
    const float* xb = xT + (size_t)(b0 + bb) * 2 * 256 * NN;
    x00 = xb[(size_t)(2 * j) * NN + n];
    x01 = xb[(size_t)(2 * j + 1) * NN + n];
    x10 = xb[(size_t)(256 + 2 * j) * NN + n];
    x11 = xb[(size_t)(256 + 2 * j + 1) * NN + n];
  }
  float FG[32];
#pragma unroll
  for (int half = 0; half < 2; half++) {
    float accf[16], accg[16];
#pragma unroll
    for (int c = 0; c < 16; c++) {
      accf[c] = fb[half * 16 + c];
      accg[c] = gb[half * 16 + c];
    }
    for (int cp = 0; cp < 32; cp++) {
      float v0, v1;
      if (FUSED) {
        float w0 = sw[cp * 2], w1 = sw[cp * 2 + 1], bc = sb[cp];
        v0 = fmaf(w0, x00, fmaf(w1, x10, bc));
        v1 = fmaf(w0, x01, fmaf(w1, x11, bc));
      } else {
        v0 = hprev[base + cp * cs];
        v1 = hprev[base + cp * cs + NN];
      }
      const float* fwp = fw + (half * 16) * 64 + cp * 2;  // [c][cp][tap]
      const float* gwp = gw + (half * 16) * 64 + cp * 2;
#pragma unroll
      for (int c = 0; c < 16; c++) {
        accf[c] = fmaf(fwp[c * 64], v0, accf[c]);
        accf[c] = fmaf(fwp[c * 64 + 1], v1, accf[c]);
        accg[c] = fmaf(gwp[c * 64], v0, accg[c]);
        accg[c] = fmaf(gwp[c * 64 + 1], v1, accg[c]);
      }
    }
#pragma unroll
    for (int c = 0; c < 16; c++) {
      float E = __expf(2.f * accf[c]);
      float th = 1.f - 2.f / (E + 1.f);          // tanh
      float sg = 1.f / (1.f + __expf(-accg[c])); // sigmoid
      FG[half * 16 + c] = th * sg;
    }
  }
  if (j == L - 1) {
    size_t tbase = ((size_t)(b0 + bb) * 32) * NN + n;
#pragma unroll
    for (int c = 0; c < 32; c++) tapL[tbase + (size_t)c * NN] = FG[c];
  }
  if (Hout == nullptr) return;  // layer 8: only the skip tap survives
#pragma unroll 2
  for (int c = 0; c < 32; c++) {
    const float* wr = cw + c * 160;
    float h = cb[c], p1 = 0.f, p2 = 0.f, q1 = 0.f, q2 = 0.f;
#pragma unroll
    for (int cp = 0; cp < 32; cp++) {
      float f = FG[cp];
      h  = fmaf(wr[cp], f, h);
      p1 = fmaf(wr[32 + cp], f, p1);
      p2 = fmaf(wr[64 + cp], f, p2);
      q1 = fmaf(wr[96 + cp], f, q1);
      q2 = fmaf(wr[128 + cp], f, q2);
    }
    // residual = hprev[2j+1] (start-conv output for layer 0)
    if (FUSED) {
      h += fmaf(sw[c * 2], x01, fmaf(sw[c * 2 + 1], x11, sb[c]));
    } else {
      h += hprev[((size_t)(bb * 32 + c) * Lp + 2 * j + 1) * NN + n];
    }
    size_t mi = (size_t)(bb * 32 + c) * L + j;
    Hout[mi * NN + n] = h;
    size_t o = mi * KP + n;
    f16 t;
    t = (f16)p1; P1aH[o] = t; P1aL[o] = (f16)(p1 - (float)t);
    t = (f16)p2; P2aH[o] = t; P2aL[o] = (f16)(p2 - (float)t);
    t = (f16)q1; P1bH[o] = t; P1bL[o] = (f16)(q1 - (float)t);
    t = (f16)q2; P2bH[o] = t; P2bL[o] = (f16)(q2 - (float)t);
  }
}

// ---------------------------------------------------------------------------
// Fused GCN node-mix GEMM, LDS-free (round-4 structure: high occupancy, loads
// straight to MFMA). Out[m,w] = BN(Cin[m,w] + sum_g A_g[m,:].(B1_g+B2_g)[w,:]).
// Block 128m x 64n; 4 waves of 64m x 32n (4x2 subtiles, mfma 16x16x32).
// A-sharing: each A fragment feeds B1 and B2 MFMAs -> 16 MFMAs per 8 loads.
__global__ __launch_bounds__(256) void mfma_gcn(MSet s,
    const float* __restrict__ Cin, float* __restrict__ Out, int M,
    const float* __restrict__ bng, const float* __restrict__ bnb, int lshift) {
  int tid = threadIdx.x;
  int wave = tid >> 6, lane = tid & 63;
  int wm = wave & 1, wn = wave >> 1;
  int m0 = blockIdx.y * 128 + wm * 64;
  int n0 = blockIdx.x * 64 + wn * 32;
  int lm = lane & 15, kq = lane >> 4;  // operand frag: row lm, k-quad kq (8 k)
  floatx4 acc[4][2];
#pragma unroll
  for (int i = 0; i < 4; i++)
#pragma unroll
    for (int j = 0; j < 2; j++) acc[i][j] = (floatx4){0.f, 0.f, 0.f, 0.f};
  size_t arow[4];
#pragma unroll
  for (int i = 0; i < 4; i++) {
    int r = m0 + i * 16 + lm;
    arow[i] = (size_t)(r < M ? r : M - 1) * KP + kq * 8;
  }
  size_t brow[2];
#pragma unroll
  for (int j = 0; j < 2; j++) brow[j] = (size_t)(n0 + j * 16 + lm) * KP + kq * 8;

  for (int gi = 0; gi < 8; gi++) {
    const f16* __restrict__ Ap = s.A[gi];
    const f16* __restrict__ B1p = s.B1[gi];
    const f16* __restrict__ B2p = s.B2[gi];
    if (B2p != nullptr) {
#pragma unroll 2
      for (int k0 = 0; k0 < KP; k0 += 32) {
        half8 av[4], b1[2], b2[2];
#pragma unroll
        for (int i = 0; i < 4; i++) av[i] = *(const half8*)(Ap + arow[i] + k0);
#pragma unroll
        for (int j = 0; j < 2; j++) b1[j] = *(const half8*)(B1p + brow[j] + k0);
#pragma unroll
        for (int j = 0; j < 2; j++) b2[j] = *(const half8*)(B2p + brow[j] + k0);
#pragma unroll
        for (int i = 0; i < 4; i++)
#pragma unroll
          for (int j = 0; j < 2; j++)
            acc[i][j] = __builtin_amdgcn_mfma_f32_16x16x32_f16(av[i], b1[j], acc[i][j], 0, 0, 0);
#pragma unroll
        for (int i = 0; i < 4; i++)
#pragma unroll
          for (int j = 0; j < 2; j++)
            acc[i][j] = __builtin_amdgcn_mfma_f32_16x16x32_f16(av[i], b2[j], acc[i][j], 0, 0, 0);
      }
    } else {
#pragma unroll 2
      for (int k0 = 0; k0 < KP; k0 += 32) {
        half8 av[4], b1[2];
#pragma unroll
        for (int i = 0; i < 4; i++) av[i] = *(const half8*)(Ap + arow[i] + k0);
#pragma unroll
        for (int j = 0; j < 2; j++) b1[j] = *(const half8*)(B1p + brow[j] + k0);
#pragma unroll
        for (int i = 0; i < 4; i++)
#pragma unroll
          for (int j = 0; j < 2; j++)
            acc[i][j] = __builtin_amdgcn_mfma_f32_16x16x32_f16(av[i], b1[j], acc[i][j], 0, 0, 0);
      }
    }
  }
  // epilogue: C/D layout col = lane&15, row = (lane>>4)*4 + reg
  int cn = lane & 15, rq = lane >> 4;
  float rs = rsqrtf(1.f + 1e-5f);
#pragma unroll
  for (int i = 0; i < 4; i++) {
#pragma unroll
    for (int r = 0; r < 4; r++) {
      int row = m0 + i * 16 + rq * 4 + r;
      if (row < M) {
        int c = (row >> lshift) & 31;  // m = (bb*32+c)*L + j
        float scale = bng[c] * rs;
        float bias = bnb[c];
#pragma unroll
        for (int j = 0; j < 2; j++) {
          int col = n0 + j * 16 + cn;
          if (col < NN) {
            size_t o = (size_t)row * NN + col;
            Out[o] = (acc[i][j][r] + Cin[o]) * scale + bias;
          }
        }
      }
    }
  }
}

// ---------------------------------------------------------------------------
// skip -> relu -> end1 -> relu -> end2. One block per (b, 20 n-values).
#define NB 20
#define NBP 21
__global__ __launch_bounds__(256) void final_kernel(const float* __restrict__ tap,
    const float* __restrict__ skw, const float* __restrict__ skb,
    const float* __restrict__ e1w, const float* __restrict__ e1b,
    const float* __restrict__ e2w, const float* __restrict__ e2b,
    float* __restrict__ out) {
  __shared__ float tapS[256][NBP];
  __shared__ float skS[256][NBP];
  __shared__ float e1S[512][NBP];
  int tid = threadIdx.x;
  int b = blockIdx.y;
  int n0 = blockIdx.x * NB;
  {
    int i = tid >> 5, c = tid & 31;
    const float* tp = tap + (((size_t)i * 8 + b) * 32 + c) * NN + n0;
#pragma unroll
    for (int v = 0; v < NB; v++) tapS[tid][v] = tp[v];
  }
  __syncthreads();
  {
    float bsum = 0.f;
#pragma unroll
    for (int i2 = 0; i2 < 8; i2++) bsum += skb[i2 * 256 + tid];
    float acc[NB];
#pragma unroll
    for (int v = 0; v < NB; v++) acc[v] = bsum;
#pragma unroll
    for (int i2 = 0; i2 < 8; i2++) {
      const float* wr = skw + ((size_t)i2 * 256 + tid) * 32;
#pragma unroll
      for (int cp = 0; cp < 32; cp++) {
        float w = wr[cp];
#pragma unroll
        for (int v = 0; v < NB; v++) acc[v] = fmaf(w, tapS[i2 * 32 + cp][v], acc[v]);
      }
    }
#pragma unroll
    for (int v = 0; v < NB; v++) skS[tid][v] = fmaxf(acc[v], 0.f);
  }
  __syncthreads();
#pragma unroll
  for (int h = 0; h < 2; h++) {
    int k = tid + h * 256;
    float bv = e1b[k];
    float acc[NB];
#pragma unroll
    for (int v = 0; v < NB; v++) acc[v] = bv;
    const float* wr = e1w + (size_t)k * 256;
    for (int o = 0; o < 256; o++) {
      float w = wr[o];
#pragma unroll
      for (int v = 0; v < NB; v++) acc[v] = fmaf(w, skS[o][v], acc[v]);
    }
#pragma unroll
    for (int v = 0; v < NB; v++) e1S[k][v] = fmaxf(acc[v], 0.f);
  }
  __syncthreads();
  if (tid < 12 * NB) {
    int q = tid / NB, v = tid % NB;
    float acc = e2b[q];
    const float* wr = e2w + (size_t)q * 512;
#pragma unroll 8
    for (int k = 0; k < 512; k++) acc = fmaf(wr[k], e1S[k][v], acc);
    out[((size_t)b * 12 + q) * NN + n0 + v] = acc;
  }
}

// ---------------------------------------------------------------------------
extern "C" void kernel_launch(void* const* d_in, const int* in_sizes, int n_in,
                              void* d_out, int out_size, void* d_ws, size_t ws_size,
                              hipStream_t stream) {
  const float* x       = (const float*)d_in[0];
  const float* A0      = (const float*)d_in[1];
  const float* start_w = (const float*)d_in[2];
  const float* start_b = (const float*)d_in[3];
  const float* filt_w  = (const float*)d_in[4];
  const float* filt_b  = (const float*)d_in[5];
  const float* gate_w  = (const float*)d_in[6];
  const float* gate_b  = (const float*)d_in[7];
  const float* skip_w  = (const float*)d_in[8];
  const float* skip_b  = (const float*)d_in[9];
  const float* gcn_w   = (const float*)d_in[10];
  const float* gcn_b   = (const float*)d_in[11];
  const float* bn_g    = (const float*)d_in[12];
  const float* bn_b    = (const float*)d_in[13];
  const float* nv1     = (const float*)d_in[14];
  const float* nv2     = (const float*)d_in[15];
  const float* e1w     = (const float*)d_in[16];
  const float* e1b     = (const float*)d_in[17];
  const float* e2w     = (const float*)d_in[18];
  const float* e2b     = (const float*)d_in[19];
  float* out = (float*)d_out;

  char* ws = (char*)d_ws;
  size_t off = 0;
  auto alloc = [&](size_t bytes) -> void* {
    void* p = (void*)(ws + off);
    off += (bytes + 255) & ~(size_t)255;
    return p;
  };
  float* adp   = (float*)alloc((size_t)NN * NN * 4);
  float* tap   = (float*)alloc((size_t)8 * 8 * 32 * NN * 4);
  float* xT    = (float*)alloc((size_t)16 * 256 * NN * 4);  // [b*2+ch][t][n]
  f16*   A0tH  = (f16*)alloc((size_t)KP * KP * 2);
  f16*   A0tL  = (f16*)alloc((size_t)KP * KP * 2);
  f16*   adptH = (f16*)alloc((size_t)KP * KP * 2);
  f16*   adptL = (f16*)alloc((size_t)KP * KP * 2);
  f16*   Q0H   = (f16*)alloc((size_t)KP * KP * 2);   // (A0^2)^T pair
  f16*   Q0L   = (f16*)alloc((size_t)KP * KP * 2);
  f16*   QdH   = (f16*)alloc((size_t)KP * KP * 2);   // (adp^2)^T pair
  f16*   QdL   = (f16*)alloc((size_t)KP * KP * 2);
  size_t fixed = off;
  // per-batch: h128 (L<=128) + h64 (L<=64) fp32 + 8 f16 arrays [32*128 x 512]
  const size_t perg = 8192000ull + 4096000ull + 8ull * 4194304ull;  // 45.84 MB
  int g = 8;
  while (g > 1 && fixed + (size_t)g * perg + 1048576 > ws_size) g >>= 1;
  float* h128 = (float*)alloc((size_t)g * 8192000ull);
  float* h64  = (float*)alloc((size_t)g * 4096000ull);
  f16* slab   = (f16*)alloc(8ull * g * 4194304ull);
  int R = g * 4096;  // rows per f16 array (layer-0 M)
  f16* P1aH = slab + 0ull * R * KP;
  f16* P1aL = slab + 1ull * R * KP;
  f16* P2aH = slab + 2ull * R * KP;
  f16* P2aL = slab + 3ull * R * KP;
  f16* P1bH = slab + 4ull * R * KP;
  f16* P1bL = slab + 5ull * R * KP;
  f16* P2bH = slab + 6ull * R * KP;
  f16* P2bL = slab + 7ull * R * KP;

  adp_kernel<<<NN, 256, 0, stream>>>(nv1, nv2, adp);
  xt_kernel<<<dim3(16, 8, 16), 256, 0, stream>>>(x, xT);
  bt_kernel<<<1024, 256, 0, stream>>>(A0, A0tH, A0tL);
  bt_kernel<<<1024, 256, 0, stream>>>(adp, adptH, adptL);
  sq_kernel<<<dim3(512, 2), 512, 0, stream>>>(A0, adp, Q0H, Q0L, QdH, QdL);
  padzero_kernel<<<(48 * R + 255) / 256, 256, 0, stream>>>((uint32_t*)slab, R);

  // out = H + P1a*A0 + P2a*A0^2 + P1b*adp + P2b*adp^2, each operand as f16
  // hi/lo pair, 3 correction passes per product (lo*lo dropped).
  MSet s{};
  s.A[0] = P1aH; s.B1[0] = A0tH;  s.B2[0] = A0tL;
  s.A[1] = P1aL; s.B1[1] = A0tH;  s.B2[1] = nullptr;
  s.A[2] = P2aH; s.B1[2] = Q0H;   s.B2[2] = Q0L;
  s.A[3] = P2aL; s.B1[3] = Q0H;   s.B2[3] = nullptr;
  s.A[4] = P1bH; s.B1[4] = adptH; s.B2[4] = adptL;
  s.A[5] = P1bL; s.B1[5] = adptH; s.B2[5] = nullptr;
  s.A[6] = P2bH; s.B1[6] = QdH;   s.B2[6] = QdL;
  s.A[7] = P2bL; s.B1[7] = QdH;   s.B2[7] = nullptr;

  for (int b0 = 0; b0 < 8; b0 += g) {
    float* hprev = nullptr;
    int Lp = 256;
    for (int i = 0; i < 8; i++) {
      int L = Lp >> 1;  // 128,64,...,1
      if (i < 7) {
        float* hout = (i & 1) ? h64 : h128;
        if (i == 0) {
          dcm_kernel<true><<<dim3(2, L, g), 256, 0, stream>>>(
              nullptr, xT, start_w, start_b,
              filt_w + i * 2048, filt_b + i * 32, gate_w + i * 2048, gate_b + i * 32,
              gcn_w + i * 5120, gcn_b + i * 32, hout,
              P1aH, P1aL, P2aH, P2aL, P1bH, P1bL, P2bH, P2bL,
              tap + (size_t)i * 8 * 32 * NN, Lp, L, b0);
        } else {
          dcm_kernel<false><<<dim3(2, L, g), 256, 0, stream>>>(
              hprev, nullptr, nullptr, nullptr,
              filt_w + i * 2048, filt_b + i * 32, gate_w + i * 2048, gate_b + i * 32,
              gcn_w + i * 5120, gcn_b + i * 32, hout,
              P1aH, P1aL, P2aH, P2aL, P1bH, P1bL, P2bH, P2bL,
              tap + (size_t)i * 8 * 32 * NN, Lp, L, b0);
        }
        int M = g * 32 * L;
        int Mb = (M + 127) / 128;
        mfma_gcn<<<dim3(8, Mb), 256, 0, stream>>>(s, hout, hout, M,
                                                  bn_g + i * 32, bn_b + i * 32, 7 - i);
        hprev = hout;
        Lp = L;
      } else {
        // layer 8: only the skip tap survives
        dcm_kernel<false><<<dim3(2, 1, g), 256, 0, stream>>>(
            hprev, nullptr, nullptr, nullptr,
            filt_w + i * 2048, filt_b + i * 32, gate_w + i * 2048, gate_b + i * 32,
            gcn_w, gcn_b, nullptr,
            P1aH, P1aL, P2aH, P2aL, P1bH, P1bL, P2bH, P2bL,
            tap + (size_t)i * 8 * 32 * NN, Lp, 1, b0);
      }
    }
  }
  final_kernel<<<dim3(25, 8), 256, 0, stream>>>(tap, skip_w, skip_b, e1w, e1b, e2w, e2b, out);
}